// Round 12
// baseline (307.135 us; speedup 1.0000x reference)
//
#include <hip/hip_runtime.h>
#include <hip/hip_bf16.h>
#include <stdint.h>

#define BATCH   4096
#define IN_DIM  1024
#define OUT_DIM 1024
#define GRID_G  8
#define K8      16384            // spline K bytes/row: 1024 i x 16 B {cos g1-8, sin g1-8}
#define KB      1024             // base K (silu plane)
#define NCHUNK  4                // split-K: 4 disjoint i-ranges of 256
#define TPITCH  8192             // T row bytes: 1024 i x (c1,s1) f32
#define WSCALE  256.0f           // spline weights scaled into e4m3 range

typedef __bf16 bf16x8 __attribute__((ext_vector_type(8)));
typedef float  f32x4  __attribute__((ext_vector_type(4)));
typedef int    i32x4  __attribute__((ext_vector_type(4)));
typedef int    i32x8  __attribute__((ext_vector_type(8)));

// i-INTERLEAVED K layout (r11->r12): K-byte = i*16 + half*8 + (g-1).
// One i-window carries cos AND sin -> one T-tile staging serves both halves
// (T read ONCE, was twice) and split-K is by disjoint i-ranges -> grid
// (8,32,4) = 1024 blocks = 4 blk/CU, the only occupancy that ever sustained
// ~1.85 TB/s (r2-r4). A-tiles generated in-LDS from T seeds by the SAME
// angle-addition recurrence as the proven r0-r7 prep (numerics preserved).

// ---------------------------------------------------------------------------
// prep: blocks [0,1024) = features, [1024,5120) = weight fold.
// feat: silu(x)->Ab bf16; T[b][i] = (cos x, sin x) f32 pair; zeroes C.
// w:    one (o,i)/thread: W8[o][i*16 + {cos g1-8, sin g1-8}] fp8, one 16-B
//       nt store (fully coalesced); Wb = sb bf16.
// ---------------------------------------------------------------------------
__global__ __launch_bounds__(256) void prep(const float* __restrict__ x,
                                            const float* __restrict__ sb,
                                            const float* __restrict__ ss,
                                            const float* __restrict__ coeff,
                                            uint8_t* __restrict__ T,
                                            uint8_t* __restrict__ W8,
                                            __bf16* __restrict__ Ab,
                                            __bf16* __restrict__ Wb,
                                            float* __restrict__ C) {
    const int tid = threadIdx.x;

    if (blockIdx.x < 1024) {
        // ---------------- features ----------------
        const int t  = blockIdx.x * 256 + tid;       // over B*I/16
        const int b  = t >> 6;
        const int i0 = (t & 63) * 16;

        {   // zero C: block covers a contiguous 16 KB region
            float4 z = make_float4(0.f, 0.f, 0.f, 0.f);
            float4* cz = (float4*)(C + (size_t)blockIdx.x * 4096);
#pragma unroll
            for (int j = 0; j < 4; ++j) cz[j * 256 + tid] = z;
        }

        float xv[16];
        {
            const f32x4* xp = (const f32x4*)(x + (size_t)b * IN_DIM + i0);
            f32x4 q0 = __builtin_nontemporal_load(xp + 0);
            f32x4 q1 = __builtin_nontemporal_load(xp + 1);
            f32x4 q2 = __builtin_nontemporal_load(xp + 2);
            f32x4 q3 = __builtin_nontemporal_load(xp + 3);
#pragma unroll
            for (int j = 0; j < 4; ++j) {
                xv[j] = q0[j]; xv[4+j] = q1[j]; xv[8+j] = q2[j]; xv[12+j] = q3[j];
            }
        }

        float c1[16], s1[16];
        bf16x8 va, vb;
#pragma unroll
        for (int j = 0; j < 16; ++j) {
            float e  = __expf(-xv[j]);
            float sl = xv[j] * __builtin_amdgcn_rcpf(1.f + e);
            if (j < 8) va[j & 7] = (__bf16)sl; else vb[j & 7] = (__bf16)sl;
            s1[j] = __sinf(xv[j]);
            c1[j] = __cosf(xv[j]);
        }
        __builtin_nontemporal_store(va, (bf16x8*)(Ab + (size_t)b * IN_DIM + i0));
        __builtin_nontemporal_store(vb, (bf16x8*)(Ab + (size_t)b * IN_DIM + i0 + 8));

        uint8_t* tp = T + (size_t)b * TPITCH + (size_t)i0 * 8;
#pragma unroll
        for (int e2 = 0; e2 < 8; ++e2) {
            f32x4 tv; tv[0] = c1[2*e2]; tv[1] = s1[2*e2]; tv[2] = c1[2*e2+1]; tv[3] = s1[2*e2+1];
            __builtin_nontemporal_store(tv, (f32x4*)(tp + e2 * 16));
        }
    } else {
        // ---------------- weight fold: one (o,i) per thread ----------------
        const int u = (blockIdx.x - 1024) * 256 + tid;   // 0 .. 1M
        const int o = u >> 10;
        const int i = u & 1023;
        const size_t oi = (size_t)o * IN_DIM + i;

        const float s = __builtin_nontemporal_load(ss + oi) * WSCALE;
        Wb[oi] = (__bf16)__builtin_nontemporal_load(sb + oi);

        const f32x4* cp0 = (const f32x4*)(coeff + ((size_t)o * IN_DIM + i) * GRID_G);
        const f32x4* cp1 = (const f32x4*)(coeff + (((size_t)OUT_DIM + o) * IN_DIM + i) * GRID_G);
        f32x4 a0 = __builtin_nontemporal_load(cp0 + 0);
        f32x4 a1 = __builtin_nontemporal_load(cp0 + 1);
        f32x4 b0 = __builtin_nontemporal_load(cp1 + 0);
        f32x4 b1 = __builtin_nontemporal_load(cp1 + 1);
        int w0 = 0, w1 = 0, w2 = 0, w3 = 0;
        w0 = __builtin_amdgcn_cvt_pk_fp8_f32(s*a0[0], s*a0[1], w0, false);
        w0 = __builtin_amdgcn_cvt_pk_fp8_f32(s*a0[2], s*a0[3], w0, true);
        w1 = __builtin_amdgcn_cvt_pk_fp8_f32(s*a1[0], s*a1[1], w1, false);
        w1 = __builtin_amdgcn_cvt_pk_fp8_f32(s*a1[2], s*a1[3], w1, true);
        w2 = __builtin_amdgcn_cvt_pk_fp8_f32(s*b0[0], s*b0[1], w2, false);
        w2 = __builtin_amdgcn_cvt_pk_fp8_f32(s*b0[2], s*b0[3], w2, true);
        w3 = __builtin_amdgcn_cvt_pk_fp8_f32(s*b1[0], s*b1[1], w3, false);
        w3 = __builtin_amdgcn_cvt_pk_fp8_f32(s*b1[2], s*b1[3], w3, true);
        i32x4 out; out[0] = w0; out[1] = w1; out[2] = w2; out[3] = w3;
        __builtin_nontemporal_store(out, (i32x4*)(W8 + (size_t)o * K8 + (size_t)i * 16));
    }
}

// ---------------------------------------------------------------------------
// Fused GEMM. Grid (8,32,4) = 1024 blocks = EXACTLY 4 blk/CU (40960 B LDS).
// Per kz: i in [kz*256, +256): 32 spline tiles (8 i each) + 4 base bf16 tiles
// (r4's proven balance). Spline tile (r4-style syncthreads schedule):
//   stage T (2 loads) + B (4 loads) ; sync ; A-gen in LDS (angle-addition
//   chain, 2 threads/row, all LDS maps <=2-way banked) ; sync ; 16 x
//   mfma_scale 16x16x128 ; sync.
// Epilogue: HW f32 atomic add into zeroed C (4 passes).
// ---------------------------------------------------------------------------
__global__ __launch_bounds__(256, 4) void gemm_all(const uint8_t* __restrict__ Tg_,
                                                   const uint8_t* __restrict__ W8,
                                                   const uint8_t* __restrict__ Ab,
                                                   const uint8_t* __restrict__ Wb,
                                                   float* __restrict__ C) {
    __shared__ __align__(16) uint8_t pool[40960];
    uint8_t* Tb = pool;                          //  8 KB [128 rows x 64 B]
    uint8_t* Bb = pool + 8192;                   // 16 KB [128 rows x 128 B]
    uint8_t* Ax = pool + 24576;                  // 16 KB [128 rows x 128 B]

    const int tid = threadIdx.x;
    const int w   = tid >> 6;
    const int l   = tid & 63;
    const int flat = blockIdx.y * 8 + blockIdx.x;
    const int xcd  = flat & 7;
    const int idx  = flat >> 3;
    const int bn   = (xcd & 1) * 4 + (idx & 3);   // N/128 = 8
    const int bm   = (xcd >> 1) * 8 + (idx >> 2); // M/128 = 32
    const int kz  = blockIdx.z;                   // 0..3: i-range [kz*256,+256)
    const int wm  = w & 1;
    const int wn  = w >> 1;

    f32x4 acc[4][4] = {};

    const int srow   = l >> 3;                  // B-staging row-in-8
    const int schunk = ((l & 7) ^ srow) * 16;   // swizzled 16B source chunk
    const int lm = l & 15;
    const int q  = l >> 4;
    const int c0 = (q * 2) << 4, c1 = (q * 2 + 1) << 4;

    // ---------------- spline phase: 32 K-tiles, fused A-gen ----------------
    {
        // T staging: rows of 64 B; lane l covers row (l>>2), chunk (l&3);
        // logical chunk ch of row r lives at LDS pos ch ^ (r&3) (pre-swizzled src).
        const int trow_l = l >> 2;              // 0..15
        const int tkey_l = trow_l & 3;          // (row&3): w*32,j*16 are 0 mod 4
        const uint8_t* Tg = Tg_ + (size_t)(bm * 128 + w * 32 + trow_l) * TPITCH
                          + kz * 2048 + (size_t)(((l & 3) ^ tkey_l) * 16);
        const uint8_t* Bg = W8 + (size_t)(bn * 128 + w * 32 + srow) * K8
                          + kz * 4096 + schunk;

        auto stageT = [&]() {                   // 2 vmem ops/wave
#pragma unroll
            for (int j = 0; j < 2; ++j)
                __builtin_amdgcn_global_load_lds(
                    (const uint32_t*)(Tg + (size_t)(j * 16) * TPITCH),
                    (uint32_t*)(Tb + w * 2048 + j * 1024), 16, 0, 0);
            Tg += 64;
        };
        auto stageB = [&]() {                   // 4 vmem ops/wave
#pragma unroll
            for (int j = 0; j < 4; ++j)
                __builtin_amdgcn_global_load_lds(
                    (const uint32_t*)(Bg + (size_t)(j * 8) * K8),
                    (uint32_t*)(Bb + (w * 32 + j * 8) * 128), 16, 0, 0);
            Bg += 128;
        };

        // A-gen: thread (r = tid>>1, half = tid&1) -> 4 i's of row r.
        const int r    = tid >> 1;
        const int half = tid & 1;
        const int tkey = r & 3;
        const int akey = r & 7;
        const uint8_t* trow = Tb + r * 64;
        uint8_t*       arow = Ax + r * 128;
        auto agen = [&]() {
#pragma unroll
            for (int c = 0; c < 2; ++c) {
                f32x4 tv = *(const f32x4*)(trow + (((half * 2 + c) ^ tkey) << 4));
#pragma unroll
                for (int e = 0; e < 2; ++e) {
                    const float cc1 = tv[e * 2], ss1 = tv[e * 2 + 1];
                    float cg = cc1, sg = ss1;
                    int w0 = 0, w1 = 0, w2 = 0, w3 = 0;
                    float cA[8], sA[8];
                    cA[0] = cg; sA[0] = sg;
#pragma unroll
                    for (int g = 1; g < 8; ++g) {
                        float cn = cg * cc1 - sg * ss1;
                        float sn = sg * cc1 + cg * ss1;
                        cg = cn; sg = sn;
                        cA[g] = cg; sA[g] = sg;
                    }
                    w0 = __builtin_amdgcn_cvt_pk_fp8_f32(cA[0], cA[1], w0, false);
                    w0 = __builtin_amdgcn_cvt_pk_fp8_f32(cA[2], cA[3], w0, true);
                    w1 = __builtin_amdgcn_cvt_pk_fp8_f32(cA[4], cA[5], w1, false);
                    w1 = __builtin_amdgcn_cvt_pk_fp8_f32(cA[6], cA[7], w1, true);
                    w2 = __builtin_amdgcn_cvt_pk_fp8_f32(sA[0], sA[1], w2, false);
                    w2 = __builtin_amdgcn_cvt_pk_fp8_f32(sA[2], sA[3], w2, true);
                    w3 = __builtin_amdgcn_cvt_pk_fp8_f32(sA[4], sA[5], w3, false);
                    w3 = __builtin_amdgcn_cvt_pk_fp8_f32(sA[6], sA[7], w3, true);
                    i32x4 out; out[0] = w0; out[1] = w1; out[2] = w2; out[3] = w3;
                    const int ich = half * 4 + c * 2 + e;     // i_local 0..7
                    *(i32x4*)(arow + ((ich ^ akey) << 4)) = out;
                }
            }
        };

        auto mfma = [&]() {
            i32x8 bf[4];
#pragma unroll
            for (int j = 0; j < 4; ++j) {
                const int row = wn * 64 + j * 16 + lm;
                const int sw  = (row & 7) << 4;
                const uint8_t* rp = Bb + row * 128;
                i32x4 lo = *(const i32x4*)(rp + (c0 ^ sw));
                i32x4 hi = *(const i32x4*)(rp + (c1 ^ sw));
                bf[j] = __builtin_shufflevector(lo, hi, 0, 1, 2, 3, 4, 5, 6, 7);
            }
#pragma unroll
            for (int i = 0; i < 4; ++i) {
                const int row = wm * 64 + i * 16 + lm;
                const int sw  = (row & 7) << 4;
                const uint8_t* rp = Ax + row * 128;
                i32x4 lo = *(const i32x4*)(rp + (c0 ^ sw));
                i32x4 hi = *(const i32x4*)(rp + (c1 ^ sw));
                i32x8 af = __builtin_shufflevector(lo, hi, 0, 1, 2, 3, 4, 5, 6, 7);
#pragma unroll
                for (int j = 0; j < 4; ++j)
                    acc[i][j] = __builtin_amdgcn_mfma_scale_f32_16x16x128_f8f6f4(
                        af, bf[j], acc[i][j], 0, 0, 0, 0x7f7f7f7f, 0, 0x7f7f7f7f);
            }
        };

        for (int t = 0; t < 32; ++t) {
            stageT(); stageB();
            __syncthreads();                     // T,B landed
            agen();
            __syncthreads();                     // Ax visible
            mfma();
            __syncthreads();                     // reads done -> next stage
        }
    }

    // undo WSCALE on the fp8 spline weights
#pragma unroll
    for (int i = 0; i < 4; ++i)
#pragma unroll
        for (int j = 0; j < 4; ++j)
            acc[i][j] *= (1.0f / WSCALE);

    // ---------------- base bf16 phase: K-slice kz (4 tiles, r4 scheme) -----
    {
        uint8_t* As = pool;                      // 16 KB
        uint8_t* Bs = pool + 16384;              // 16 KB
        const uint8_t* Ag = Ab + (size_t)(bm * 128 + w * 32 + srow) * (KB * 2) + kz * 512 + schunk;
        const uint8_t* Bg = Wb + (size_t)(bn * 128 + w * 32 + srow) * (KB * 2) + kz * 512 + schunk;

        for (int t = 0; t < 4; ++t) {
#pragma unroll
            for (int j = 0; j < 4; ++j) {
                __builtin_amdgcn_global_load_lds(
                    (const uint32_t*)(Ag + (size_t)(j * 8) * (KB * 2)),
                    (uint32_t*)(As + (w * 32 + j * 8) * 128), 16, 0, 0);
                __builtin_amdgcn_global_load_lds(
                    (const uint32_t*)(Bg + (size_t)(j * 8) * (KB * 2)),
                    (uint32_t*)(Bs + (w * 32 + j * 8) * 128), 16, 0, 0);
            }
            Ag += 128; Bg += 128;
            __syncthreads();

#pragma unroll
            for (int h = 0; h < 2; ++h) {
                bf16x8 af[4], bfr[4];
#pragma unroll
                for (int i = 0; i < 4; ++i) {
                    const int row = wm * 64 + i * 16 + lm;
                    af[i] = *(const bf16x8*)(As + row * 128 + ((((h * 4 + q) ^ (row & 7))) << 4));
                }
#pragma unroll
                for (int j = 0; j < 4; ++j) {
                    const int row = wn * 64 + j * 16 + lm;
                    bfr[j] = *(const bf16x8*)(Bs + row * 128 + ((((h * 4 + q) ^ (row & 7))) << 4));
                }
#pragma unroll
                for (int i = 0; i < 4; ++i)
#pragma unroll
                    for (int j = 0; j < 4; ++j)
                        acc[i][j] = __builtin_amdgcn_mfma_f32_16x16x32_bf16(af[i], bfr[j], acc[i][j], 0, 0, 0);
            }
            __syncthreads();
        }
    }

    // epilogue: C/D layout col = lane&15, row = (lane>>4)*4 + reg
    const int row0 = bm * 128 + wm * 64 + q * 4;
    const int col0 = bn * 128 + wn * 64 + lm;
#pragma unroll
    for (int i = 0; i < 4; ++i)
#pragma unroll
        for (int j = 0; j < 4; ++j)
#pragma unroll
            for (int r = 0; r < 4; ++r)
                unsafeAtomicAdd(&C[(size_t)(row0 + i * 16 + r) * OUT_DIM + col0 + j * 16],
                                acc[i][j][r]);
}

// ---------------------------------------------------------------------------
extern "C" void kernel_launch(void* const* d_in, const int* in_sizes, int n_in,
                              void* d_out, int out_size, void* d_ws, size_t ws_size,
                              hipStream_t stream) {
    const float* x     = (const float*)d_in[0];   // (B, I)
    const float* sb    = (const float*)d_in[1];   // (O, I)
    const float* ss    = (const float*)d_in[2];   // (O, I)
    const float* coeff = (const float*)d_in[3];   // (2, O, I, G)
    float* out = (float*)d_out;                   // (B, O)

    uint8_t* T  = (uint8_t*)d_ws;                          // 4096*8192  = 33.6 MB
    uint8_t* W8 = T + (size_t)BATCH * TPITCH;              // 1024*16384 = 16.8 MB
    __bf16*  Ab = (__bf16*)(W8 + (size_t)OUT_DIM * K8);    // 4096*1024 bf16 = 8.4 MB
    __bf16*  Wb = Ab + (size_t)BATCH * KB;                 // 1024*1024 bf16 = 2.1 MB

    hipLaunchKernelGGL(prep, dim3(1024 + 4096), dim3(256), 0, stream,
                       x, sb, ss, coeff, T, W8, Ab, Wb, out);
    hipLaunchKernelGGL(gemm_all, dim3(OUT_DIM / 128, BATCH / 128, NCHUNK), dim3(256), 0, stream,
                       T, W8, (const uint8_t*)Ab, (const uint8_t*)Wb, out);
}